// Round 10
// baseline (130.073 us; speedup 1.0000x reference)
//
#include <hip/hip_runtime.h>
#include <hip/hip_bf16.h>
#include <math.h>

// Problem: B_SZ=2, L=2048, D=1024, N=16.  M = B_SZ*L = 4096.
// y[m,d] = x[m,d] * softplus((x@W1^T)[m,d] + b1[d]) * s[m]
// s[m]   = sum_n (x_m . W2_n + b2_n) * (x_m . W3_n + b3_n)
// A is unused (multiplies a zero-initialized h in the reference).
// Pipeline: convert (x,W1->bf16; pack Wc=[W2;W3] bf16) -> s_mfma -> gemm.
// NOTE (round-6): never runtime-index MFMA fragment arrays (scratch demotion).
// NOTE (round-9): 64^2/4-wave gemm is LDS-issue-bound (R=16 FLOP/B); fix is
// a 64x64 WAVE tile (R=32) via single-wave blocks, not more barrier tuning.

typedef __bf16 bf16x8 __attribute__((ext_vector_type(8)));
typedef __bf16 bf16x4 __attribute__((ext_vector_type(4)));
typedef float  f32x4  __attribute__((ext_vector_type(4)));

#define MDIM 4096
#define KDIM 1024
#define NDIM 1024

// async global->LDS, 16B per lane; LDS dest = wave-uniform base + lane*16.
__device__ __forceinline__ void async16(const void* g, void* l) {
    __builtin_amdgcn_global_load_lds(
        (const __attribute__((address_space(1))) void*)g,
        (__attribute__((address_space(3))) void*)l, 16, 0, 0);
}

__device__ __forceinline__ float softplus_f(float z) {
    return fmaxf(z, 0.f) + log1pf(__expf(-fabsf(z)));
}

// ============ convert: pure streaming x,W1 -> bf16; pack Wc=[W2;W3] ============
#define NX4 ((MDIM * KDIM) / 4)   // 1048576
#define NW4 ((KDIM * NDIM) / 4)   // 262144
#define NC4 ((32 * KDIM) / 4)     // 8192
__global__ __launch_bounds__(256)
void convert_kernel(const float* __restrict__ x, const float* __restrict__ W1,
                    const float* __restrict__ W2, const float* __restrict__ W3,
                    __bf16* __restrict__ xb, __bf16* __restrict__ w1b,
                    __bf16* __restrict__ wcb) {
    const size_t i = (size_t)blockIdx.x * 256 + threadIdx.x;
    if (i < NX4) {
        float4 v = reinterpret_cast<const float4*>(x)[i];
        bf16x4 h = { (__bf16)v.x, (__bf16)v.y, (__bf16)v.z, (__bf16)v.w };
        reinterpret_cast<bf16x4*>(xb)[i] = h;
    } else if (i < NX4 + NW4) {
        const size_t j = i - NX4;
        float4 v = reinterpret_cast<const float4*>(W1)[j];
        bf16x4 h = { (__bf16)v.x, (__bf16)v.y, (__bf16)v.z, (__bf16)v.w };
        reinterpret_cast<bf16x4*>(w1b)[j] = h;
    } else {
        const size_t j = i - NX4 - NW4;
        if (j < NC4) {
            const int row = (int)(j >> 8);     // 0..31
            const int c4  = (int)(j & 255);    // 0..255
            const float* __restrict__ src = (row < 16)
                ? (W2 + (size_t)row * KDIM) : (W3 + (size_t)(row - 16) * KDIM);
            float4 v = reinterpret_cast<const float4*>(src)[c4];
            bf16x4 h = { (__bf16)v.x, (__bf16)v.y, (__bf16)v.z, (__bf16)v.w };
            reinterpret_cast<bf16x4*>(wcb)[row * 256 + c4] = h;
        }
    }
}
#define CONV_GRID ((NX4 + NW4 + NC4) / 256)

// ============ s kernel (MFMA, lean): s[m] = sum_n (Bm+b2)(Cm+b3) ============
// 256 blocks x 16 rows. 4 waves K-split (256 k each). x rows staged bf16 in
// LDS (padded); Wc fragments gathered straight from L2-hot global wcb.
__global__ __launch_bounds__(256)
void s_mfma(const __bf16* __restrict__ xb, const __bf16* __restrict__ wcb,
            const float* __restrict__ b2, const float* __restrict__ b3,
            float* __restrict__ s) {
    __shared__ __align__(16) __bf16 xs[16 * 1032];   // 33 KB (+8 pad)
    __shared__ float red[4][2][16][16];              // 8 KB
    const int t = threadIdx.x;
    const int wave = t >> 6, lane = t & 63;
    const int lrow = lane & 15, quad = lane >> 4;
    const size_t m0 = (size_t)blockIdx.x * 16;
    const int wk0 = wave * 256;

    // stage 16 rows of xb -> LDS (coalesced bf16x8)
#pragma unroll
    for (int i = 0; i < 8; ++i) {
        const int idx = i * 256 + t;          // 0..2047
        const int row = idx >> 7;             // 0..15
        const int c8  = (idx & 127) * 8;      // 0..1016
        bf16x8 v = *reinterpret_cast<const bf16x8*>(xb + (m0 + row) * KDIM + c8);
        *reinterpret_cast<bf16x8*>(&xs[row * 1032 + c8]) = v;
    }
    __syncthreads();

    f32x4 acc[2] = {};
#pragma unroll
    for (int ks = 0; ks < 256; ks += 32) {
        bf16x8 a = *reinterpret_cast<const bf16x8*>(
            &xs[lrow * 1032 + wk0 + ks + quad * 8]);
        bf16x8 b0 = *reinterpret_cast<const bf16x8*>(
            wcb + (size_t)lrow * KDIM + wk0 + ks + quad * 8);
        acc[0] = __builtin_amdgcn_mfma_f32_16x16x32_bf16(a, b0, acc[0], 0, 0, 0);
        bf16x8 b1 = *reinterpret_cast<const bf16x8*>(
            wcb + (size_t)(16 + lrow) * KDIM + wk0 + ks + quad * 8);
        acc[1] = __builtin_amdgcn_mfma_f32_16x16x32_bf16(a, b1, acc[1], 0, 0, 0);
    }
    // D layout: row = quad*4 + r (x-row), col = lrow (n)
#pragma unroll
    for (int r = 0; r < 4; ++r) {
        red[wave][0][quad * 4 + r][lrow] = acc[0][r];
        red[wave][1][quad * 4 + r][lrow] = acc[1][r];
    }
    __syncthreads();

    {
        const int row = t >> 4, n = t & 15;
        float Bv = red[0][0][row][n] + red[1][0][row][n]
                 + red[2][0][row][n] + red[3][0][row][n] + b2[n];
        float Cv = red[0][1][row][n] + red[1][1][row][n]
                 + red[2][1][row][n] + red[3][1][row][n] + b3[n];
        float p = Bv * Cv;
        p += __shfl_xor(p, 1);
        p += __shfl_xor(p, 2);
        p += __shfl_xor(p, 4);
        p += __shfl_xor(p, 8);
        if (n == 0) s[m0 + row] = p;
    }
}

// ============ main GEMM: y = x * softplus(xb@w1b^T + b1) * s ============
// SINGLE-WAVE blocks (64 thr): each wave owns a full 64x64 tile (af4 x bf4,
// 16 MFMA per 8 ds_read_b128 -> R=32 FLOP/LDS-byte) with per-wave
// double-buffered LDS. 1024 blocks ~= 4-5/CU (LDS 32 KB); __syncthreads on a
// 1-wave block is just the vmcnt drain — no cross-wave barrier convoy.
#define GBM 64
#define GBN 64
#define GBK 64
#define NIT (KDIM / GBK)
__global__ __launch_bounds__(64)
void gemm_wave(const __bf16* __restrict__ xb, const __bf16* __restrict__ w1b,
               const float* __restrict__ x, const float* __restrict__ b1,
               const float* __restrict__ s, float* __restrict__ y) {
    __shared__ __align__(16) __bf16 As[2][GBM * GBK];  // 16 KB
    __shared__ __align__(16) __bf16 Bs[2][GBN * GBK];  // 16 KB
    const int bm = blockIdx.x, bn = blockIdx.y;   // consecutive blocks share bn
    const int lane = threadIdx.x;                 // 0..63
    const int lrow = lane & 15, quad = lane >> 4;
    const int srow = lane >> 3;                 // row within 8-row chunk
    const int scol = ((lane & 7) ^ srow) * 8;   // XOR-swizzled source col group
    const size_t m0 = (size_t)bm * GBM, n0 = (size_t)bn * GBN;

    f32x4 acc[4][4] = {};

    // prologue: fill buffer 0 (A: 8 chunks of 8 rows; B: same)
#pragma unroll
    for (int q = 0; q < 8; ++q) {
        int row = q * 8 + srow;
        async16(xb + (m0 + row) * KDIM + scol, &As[0][q * 512]);
        async16(w1b + (n0 + row) * KDIM + scol, &Bs[0][q * 512]);
    }

    for (int it = 0; it < NIT; ++it) {
        const int p = it & 1;
        __syncthreads();   // 1-wave block: vmcnt drain only (buf p ready)

        if (it + 1 < NIT) {
            const int k1 = (it + 1) * GBK;
#pragma unroll
            for (int q = 0; q < 8; ++q) {
                int row = q * 8 + srow;
                async16(xb + (m0 + row) * KDIM + k1 + scol, &As[p ^ 1][q * 512]);
                async16(w1b + (n0 + row) * KDIM + k1 + scol, &Bs[p ^ 1][q * 512]);
            }
        }

#pragma unroll
        for (int kk = 0; kk < GBK; kk += 32) {
            const int cg = (kk >> 3) + quad;  // logical col group 0..7
            bf16x8 af[4], bfr[4];
#pragma unroll
            for (int mi = 0; mi < 4; ++mi) {
                int row = mi * 16 + lrow;
                af[mi] = *reinterpret_cast<const bf16x8*>(
                    &As[p][row * GBK + ((cg ^ (row & 7)) << 3)]);
            }
#pragma unroll
            for (int ni = 0; ni < 4; ++ni) {
                int row = ni * 16 + lrow;
                bfr[ni] = *reinterpret_cast<const bf16x8*>(
                    &Bs[p][row * GBK + ((cg ^ (row & 7)) << 3)]);
            }
#pragma unroll
            for (int mi = 0; mi < 4; ++mi)
#pragma unroll
                for (int ni = 0; ni < 4; ++ni)
                    acc[mi][ni] = __builtin_amdgcn_mfma_f32_16x16x32_bf16(
                        af[mi], bfr[ni], acc[mi][ni], 0, 0, 0);
        }
    }

    // ---- epilogue: y = x * softplus(acc + b1) * s ----
#pragma unroll
    for (int ni = 0; ni < 4; ++ni) {
        const size_t gn = n0 + ni * 16 + lrow;
        const float bias = b1[gn];
#pragma unroll
        for (int mi = 0; mi < 4; ++mi) {
#pragma unroll
            for (int r = 0; r < 4; ++r) {
                const size_t gm = m0 + mi * 16 + quad * 4 + r;
                float z = acc[mi][ni][r] + bias;
                y[gm * NDIM + gn] = x[gm * NDIM + gn] * softplus_f(z) * s[gm];
            }
        }
    }
}

// ================= fallback path (ws too small): round-0 kernels =============
__global__ __launch_bounds__(256)
void s_kernel_fb(const float* __restrict__ x,
                 const float* __restrict__ W2, const float* __restrict__ b2,
                 const float* __restrict__ W3, const float* __restrict__ b3,
                 float* __restrict__ s) {
    __shared__ float xs[1024];
    __shared__ float ps[8][32];
    __shared__ float bc[32];
    const int m = blockIdx.x;
    const int t = threadIdx.x;
    reinterpret_cast<float4*>(xs)[t] =
        reinterpret_cast<const float4*>(x + (size_t)m * 1024)[t];
    __syncthreads();
    const int n = t & 15;
    const int mat = (t >> 4) & 1;
    const int seg = t >> 5;
    const float* __restrict__ W = mat ? W3 : W2;
    const float* __restrict__ wr = W + (size_t)n * 1024 + seg * 128;
    const float* __restrict__ xr = xs + seg * 128;
    float p = 0.f;
#pragma unroll
    for (int i = 0; i < 128; i += 4) {
        float4 w4 = *reinterpret_cast<const float4*>(wr + i);
        float4 x4 = *reinterpret_cast<const float4*>(xr + i);
        p += w4.x * x4.x + w4.y * x4.y + w4.z * x4.z + w4.w * x4.w;
    }
    ps[seg][t & 31] = p;
    __syncthreads();
    if (t < 32) {
        float tot = 0.f;
#pragma unroll
        for (int g = 0; g < 8; ++g) tot += ps[g][t];
        tot += (t < 16) ? b2[t] : b3[t - 16];
        bc[t] = tot;
    }
    __syncthreads();
    if (t == 0) {
        float ss = 0.f;
#pragma unroll
        for (int nn = 0; nn < 16; ++nn) ss += bc[nn] * bc[16 + nn];
        s[m] = ss;
    }
}

#define BM 128
#define BN 64
#define BK 64
#define LDK 72
__global__ __launch_bounds__(256)
void gemm_fused_fb(const float* __restrict__ x, const float* __restrict__ W1,
                   const float* __restrict__ b1, const float* __restrict__ s,
                   float* __restrict__ y) {
    __shared__ __align__(16) __bf16 As[BM * LDK];
    __shared__ __align__(16) __bf16 Bs[BN * LDK];
    const int bm = blockIdx.y;
    const int bn = blockIdx.x;
    const int t = threadIdx.x;
    const int wave = t >> 6;
    const int lane = t & 63;
    const int wm = (wave >> 1) * 64;
    const int wn = (wave & 1) * 32;
    const int lrow = lane & 15;
    const int quad = lane >> 4;
    f32x4 acc[4][2] = {};
    const int rbase = t >> 4;
    const int scol = (t & 15) * 4;
    const float* __restrict__ xg = x + (size_t)(bm * BM) * KDIM + scol;
    const float* __restrict__ wg = W1 + (size_t)(bn * BN) * KDIM + scol;
    for (int k0 = 0; k0 < KDIM; k0 += BK) {
#pragma unroll
        for (int rr = 0; rr < 8; ++rr) {
            int row = rr * 16 + rbase;
            float4 v = *reinterpret_cast<const float4*>(xg + (size_t)row * KDIM + k0);
            bf16x4 h = { (__bf16)v.x, (__bf16)v.y, (__bf16)v.z, (__bf16)v.w };
            *reinterpret_cast<bf16x4*>(&As[row * LDK + scol]) = h;
        }
#pragma unroll
        for (int rr = 0; rr < 4; ++rr) {
            int row = rr * 16 + rbase;
            float4 v = *reinterpret_cast<const float4*>(wg + (size_t)row * KDIM + k0);
            bf16x4 h = { (__bf16)v.x, (__bf16)v.y, (__bf16)v.z, (__bf16)v.w };
            *reinterpret_cast<bf16x4*>(&Bs[row * LDK + scol]) = h;
        }
        __syncthreads();
#pragma unroll
        for (int kk = 0; kk < BK; kk += 32) {
            bf16x8 af[4];
            bf16x8 bfr[2];
#pragma unroll
            for (int mi = 0; mi < 4; ++mi)
                af[mi] = *reinterpret_cast<const bf16x8*>(
                    &As[(wm + mi * 16 + lrow) * LDK + kk + quad * 8]);
#pragma unroll
            for (int ni = 0; ni < 2; ++ni)
                bfr[ni] = *reinterpret_cast<const bf16x8*>(
                    &Bs[(wn + ni * 16 + lrow) * LDK + kk + quad * 8]);
#pragma unroll
            for (int mi = 0; mi < 4; ++mi)
#pragma unroll
                for (int ni = 0; ni < 2; ++ni)
                    acc[mi][ni] = __builtin_amdgcn_mfma_f32_16x16x32_bf16(
                        af[mi], bfr[ni], acc[mi][ni], 0, 0, 0);
        }
        __syncthreads();
    }
    const int gmb = bm * BM + wm;
    const int gnb = bn * BN + wn;
#pragma unroll
    for (int ni = 0; ni < 2; ++ni) {
        const int gn = gnb + ni * 16 + lrow;
        const float bias = b1[gn];
#pragma unroll
        for (int mi = 0; mi < 4; ++mi) {
            const int gm0 = gmb + mi * 16 + quad * 4;
#pragma unroll
            for (int r = 0; r < 4; ++r) {
                const int gm = gm0 + r;
                float z = acc[mi][ni][r] + bias;
                y[(size_t)gm * NDIM + gn] =
                    x[(size_t)gm * NDIM + gn] * softplus_f(z) * s[gm];
            }
        }
    }
}

extern "C" void kernel_launch(void* const* d_in, const int* in_sizes, int n_in,
                              void* d_out, int out_size, void* d_ws, size_t ws_size,
                              hipStream_t stream) {
    const float* x  = (const float*)d_in[0];
    const float* W1 = (const float*)d_in[1];
    const float* b1 = (const float*)d_in[2];
    const float* W2 = (const float*)d_in[3];
    const float* b2 = (const float*)d_in[4];
    const float* W3 = (const float*)d_in[5];
    const float* b3 = (const float*)d_in[6];
    // d_in[7] = A : unused

    float* y = (float*)d_out;

    const size_t XB_BYTES = (size_t)MDIM * KDIM * 2;   // 8 MB
    const size_t WB_BYTES = (size_t)NDIM * KDIM * 2;   // 2 MB
    const size_t WC_BYTES = (size_t)32 * KDIM * 2;     // 64 KB
    const size_t S_BYTES  = (size_t)MDIM * 4;          // 16 KB

    if (ws_size >= XB_BYTES + WB_BYTES + WC_BYTES + S_BYTES) {
        __bf16* xb  = (__bf16*)d_ws;
        __bf16* w1b = (__bf16*)((char*)d_ws + XB_BYTES);
        __bf16* wcb = (__bf16*)((char*)d_ws + XB_BYTES + WB_BYTES);
        float*  s   = (float*)((char*)d_ws + XB_BYTES + WB_BYTES + WC_BYTES);
        convert_kernel<<<dim3(CONV_GRID), dim3(256), 0, stream>>>(
            x, W1, W2, W3, xb, w1b, wcb);
        s_mfma<<<dim3(MDIM / 16), dim3(256), 0, stream>>>(xb, wcb, b2, b3, s);
        gemm_wave<<<dim3(MDIM / GBM, NDIM / GBN), dim3(64), 0, stream>>>(
            xb, w1b, x, b1, s, y);
    } else {
        float* s = (float*)d_ws;
        s_kernel_fb<<<dim3(MDIM), dim3(256), 0, stream>>>(x, W2, b2, W3, b3, s);
        gemm_fused_fb<<<dim3(NDIM / BN, MDIM / BM), dim3(256), 0, stream>>>(x, W1, b1, s, y);
    }
}

// Round 11
// 111.107 us; speedup vs baseline: 1.1707x; 1.1707x over previous
//
#include <hip/hip_runtime.h>
#include <hip/hip_bf16.h>
#include <math.h>

// Problem: B_SZ=2, L=2048, D=1024, N=16.  M = B_SZ*L = 4096.
// y[m,d] = x[m,d] * softplus((x@W1^T)[m,d] + b1[d]) * s[m]
// s[m]   = sum_n (x_m . W2_n + b2_n) * (x_m . W3_n + b3_n)
// A is unused (multiplies a zero-initialized h in the reference).
// Pipeline: prep2 (x->bf16 LDS+global, W1 slice ->bf16, s via MFMA with
// inline-converted W2/W3 fragments) -> gemm (round-9 best: 64x64x128,
// 1024 blocks = 4/CU, XOR-swizzled async16 staging).
// NOTE (round-6): never runtime-index MFMA fragment arrays (scratch demotion).
// NOTE (round-10): single-wave blocks kill latency hiding (4 waves/CU,
// MfmaUtil 3%) — R and occupancy must rise together.

typedef __bf16 bf16x8 __attribute__((ext_vector_type(8)));
typedef __bf16 bf16x4 __attribute__((ext_vector_type(4)));
typedef float  f32x4  __attribute__((ext_vector_type(4)));

#define MDIM 4096
#define KDIM 1024
#define NDIM 1024

// async global->LDS, 16B per lane; LDS dest = wave-uniform base + lane*16.
__device__ __forceinline__ void async16(const void* g, void* l) {
    __builtin_amdgcn_global_load_lds(
        (const __attribute__((address_space(1))) void*)g,
        (__attribute__((address_space(3))) void*)l, 16, 0, 0);
}

__device__ __forceinline__ float softplus_f(float z) {
    return fmaxf(z, 0.f) + log1pf(__expf(-fabsf(z)));
}

__device__ __forceinline__ bf16x8 cvt8(float4 v0, float4 v1) {
    bf16x8 h = { (__bf16)v0.x, (__bf16)v0.y, (__bf16)v0.z, (__bf16)v0.w,
                 (__bf16)v1.x, (__bf16)v1.y, (__bf16)v1.z, (__bf16)v1.w };
    return h;
}

// ====== prep2: x -> bf16 (LDS + global), W1 slice -> bf16, s via MFMA ======
// 256 blocks x 256 thr; block b owns x rows 16b..16b+15. 4 waves K-split
// (256 k each); Wc=[W2;W3] fragments read fp32 from L2-hot global + inline cvt.
__global__ __launch_bounds__(256)
void prep2(const float* __restrict__ x, const float* __restrict__ W1,
           const float* __restrict__ W2, const float* __restrict__ b2,
           const float* __restrict__ W3, const float* __restrict__ b3,
           __bf16* __restrict__ xb, __bf16* __restrict__ w1b,
           float* __restrict__ s) {
    __shared__ __align__(16) __bf16 xs[16 * 1032];   // 33 KB (+8 pad)
    __shared__ float red[4][2][16][16];              // 8 KB
    const int t = threadIdx.x;
    const int wave = t >> 6, lane = t & 63;
    const int lrow = lane & 15, quad = lane >> 4;
    const size_t m0 = (size_t)blockIdx.x * 16;
    const int wk0 = wave * 256;

    // ---- W1 slice -> bf16 (1024 float4 per block) ----
    {
        const float4* src = reinterpret_cast<const float4*>(W1) + (size_t)blockIdx.x * 1024;
        bf16x4* dst = reinterpret_cast<bf16x4*>(w1b) + (size_t)blockIdx.x * 1024;
#pragma unroll
        for (int i = 0; i < 4; ++i) {
            float4 v = src[i * 256 + t];
            bf16x4 h = { (__bf16)v.x, (__bf16)v.y, (__bf16)v.z, (__bf16)v.w };
            dst[i * 256 + t] = h;
        }
    }

    // ---- x rows: fp32 -> bf16, to LDS and global xb (coalesced) ----
#pragma unroll
    for (int i = 0; i < 16; ++i) {
        float4 v = *reinterpret_cast<const float4*>(x + (m0 + i) * KDIM + t * 4);
        bf16x4 h = { (__bf16)v.x, (__bf16)v.y, (__bf16)v.z, (__bf16)v.w };
        *reinterpret_cast<bf16x4*>(&xs[i * 1032 + t * 4]) = h;
        *reinterpret_cast<bf16x4*>(xb + (m0 + i) * KDIM + t * 4) = h;
    }
    __syncthreads();

    // ---- per-wave K-split MFMA; W fragments from fp32 global + inline cvt ----
    f32x4 acc[2] = {};
#pragma unroll
    for (int ks = 0; ks < 256; ks += 32) {
        bf16x8 a = *reinterpret_cast<const bf16x8*>(
            &xs[lrow * 1032 + wk0 + ks + quad * 8]);
        {
            const float* p2 = W2 + (size_t)lrow * KDIM + wk0 + ks + quad * 8;
            float4 v0 = *reinterpret_cast<const float4*>(p2);
            float4 v1 = *reinterpret_cast<const float4*>(p2 + 4);
            acc[0] = __builtin_amdgcn_mfma_f32_16x16x32_bf16(a, cvt8(v0, v1), acc[0], 0, 0, 0);
        }
        {
            const float* p3 = W3 + (size_t)lrow * KDIM + wk0 + ks + quad * 8;
            float4 v0 = *reinterpret_cast<const float4*>(p3);
            float4 v1 = *reinterpret_cast<const float4*>(p3 + 4);
            acc[1] = __builtin_amdgcn_mfma_f32_16x16x32_bf16(a, cvt8(v0, v1), acc[1], 0, 0, 0);
        }
    }
    // D layout: row = quad*4 + r (x-row), col = lrow (n)
#pragma unroll
    for (int r = 0; r < 4; ++r) {
        red[wave][0][quad * 4 + r][lrow] = acc[0][r];
        red[wave][1][quad * 4 + r][lrow] = acc[1][r];
    }
    __syncthreads();

    {
        const int row = t >> 4, n = t & 15;
        float Bv = red[0][0][row][n] + red[1][0][row][n]
                 + red[2][0][row][n] + red[3][0][row][n] + b2[n];
        float Cv = red[0][1][row][n] + red[1][1][row][n]
                 + red[2][1][row][n] + red[3][1][row][n] + b3[n];
        float p = Bv * Cv;
        p += __shfl_xor(p, 1);
        p += __shfl_xor(p, 2);
        p += __shfl_xor(p, 4);
        p += __shfl_xor(p, 8);
        if (n == 0) s[m0 + row] = p;
    }
}

// ============ main GEMM: y = x * softplus(xb@w1b^T + b1) * s ============
// Round-9 best: 64x64x128 tiles -> 1024 blocks (4/CU). XOR-swizzled LDS
// (16 col-groups), async16 staging, 8 barrier pairs.
#define GBM 64
#define GBN 64
#define GBK 128
__global__ __launch_bounds__(256, 4)
void gemm_bf(const __bf16* __restrict__ xb, const __bf16* __restrict__ w1b,
             const float* __restrict__ x, const float* __restrict__ b1,
             const float* __restrict__ s, float* __restrict__ y) {
    __shared__ __align__(16) __bf16 As[GBM * GBK];  // 16 KB
    __shared__ __align__(16) __bf16 Bs[GBN * GBK];  // 16 KB
    const int bm = blockIdx.y, bn = blockIdx.x;
    const int t = threadIdx.x;
    const int wave = t >> 6, lane = t & 63;
    const int wm = (wave >> 1) * 32, wn = (wave & 1) * 32;
    const int lrow = lane & 15, quad = lane >> 4;
    const int sr  = lane >> 4;      // row within 4-row staging chunk
    const int pcg = lane & 15;      // physical col group (8 bf16 each)
    const size_t m0 = (size_t)bm * GBM, n0 = (size_t)bn * GBN;

    f32x4 acc[2][2] = {};

    for (int k0 = 0; k0 < KDIM; k0 += GBK) {
#pragma unroll
        for (int i = 0; i < 4; ++i) {
            int q = wave * 4 + i;             // 0..15
            int row = q * 4 + sr;             // 0..63
            int lcg = pcg ^ (row & 15);       // logical col group to fetch
            async16(xb + (m0 + row) * KDIM + k0 + lcg * 8, &As[q * 512]);
            async16(w1b + (n0 + row) * KDIM + k0 + lcg * 8, &Bs[q * 512]);
        }
        __syncthreads();

#pragma unroll
        for (int kk = 0; kk < GBK; kk += 32) {
            const int cg = (kk >> 3) + quad;  // logical col group 0..15
            bf16x8 af[2], bfr[2];
#pragma unroll
            for (int mi = 0; mi < 2; ++mi) {
                int row = wm + mi * 16 + lrow;
                af[mi] = *reinterpret_cast<const bf16x8*>(
                    &As[row * GBK + ((cg ^ (row & 15)) << 3)]);
            }
#pragma unroll
            for (int ni = 0; ni < 2; ++ni) {
                int row = wn + ni * 16 + lrow;
                bfr[ni] = *reinterpret_cast<const bf16x8*>(
                    &Bs[row * GBK + ((cg ^ (row & 15)) << 3)]);
            }
#pragma unroll
            for (int mi = 0; mi < 2; ++mi)
#pragma unroll
                for (int ni = 0; ni < 2; ++ni)
                    acc[mi][ni] = __builtin_amdgcn_mfma_f32_16x16x32_bf16(
                        af[mi], bfr[ni], acc[mi][ni], 0, 0, 0);
        }
        __syncthreads();
    }

    // ---- epilogue: y = x * softplus(acc + b1) * s ----
#pragma unroll
    for (int ni = 0; ni < 2; ++ni) {
        const size_t gn = n0 + wn + ni * 16 + lrow;
        const float bias = b1[gn];
#pragma unroll
        for (int mi = 0; mi < 2; ++mi) {
#pragma unroll
            for (int r = 0; r < 4; ++r) {
                const size_t gm = m0 + wm + mi * 16 + quad * 4 + r;
                float z = acc[mi][ni][r] + bias;
                y[gm * NDIM + gn] = x[gm * NDIM + gn] * softplus_f(z) * s[gm];
            }
        }
    }
}

// ================= fallback path (ws too small): round-0 kernels =============
__global__ __launch_bounds__(256)
void s_kernel_fb(const float* __restrict__ x,
                 const float* __restrict__ W2, const float* __restrict__ b2,
                 const float* __restrict__ W3, const float* __restrict__ b3,
                 float* __restrict__ s) {
    __shared__ float xs[1024];
    __shared__ float ps[8][32];
    __shared__ float bc[32];
    const int m = blockIdx.x;
    const int t = threadIdx.x;
    reinterpret_cast<float4*>(xs)[t] =
        reinterpret_cast<const float4*>(x + (size_t)m * 1024)[t];
    __syncthreads();
    const int n = t & 15;
    const int mat = (t >> 4) & 1;
    const int seg = t >> 5;
    const float* __restrict__ W = mat ? W3 : W2;
    const float* __restrict__ wr = W + (size_t)n * 1024 + seg * 128;
    const float* __restrict__ xr = xs + seg * 128;
    float p = 0.f;
#pragma unroll
    for (int i = 0; i < 128; i += 4) {
        float4 w4 = *reinterpret_cast<const float4*>(wr + i);
        float4 x4 = *reinterpret_cast<const float4*>(xr + i);
        p += w4.x * x4.x + w4.y * x4.y + w4.z * x4.z + w4.w * x4.w;
    }
    ps[seg][t & 31] = p;
    __syncthreads();
    if (t < 32) {
        float tot = 0.f;
#pragma unroll
        for (int g = 0; g < 8; ++g) tot += ps[g][t];
        tot += (t < 16) ? b2[t] : b3[t - 16];
        bc[t] = tot;
    }
    __syncthreads();
    if (t == 0) {
        float ss = 0.f;
#pragma unroll
        for (int nn = 0; nn < 16; ++nn) ss += bc[nn] * bc[16 + nn];
        s[m] = ss;
    }
}

#define BM 128
#define BN 64
#define BK 64
#define LDK 72
__global__ __launch_bounds__(256)
void gemm_fused_fb(const float* __restrict__ x, const float* __restrict__ W1,
                   const float* __restrict__ b1, const float* __restrict__ s,
                   float* __restrict__ y) {
    __shared__ __align__(16) __bf16 As[BM * LDK];
    __shared__ __align__(16) __bf16 Bs[BN * LDK];
    const int bm = blockIdx.y;
    const int bn = blockIdx.x;
    const int t = threadIdx.x;
    const int wave = t >> 6;
    const int lane = t & 63;
    const int wm = (wave >> 1) * 64;
    const int wn = (wave & 1) * 32;
    const int lrow = lane & 15;
    const int quad = lane >> 4;
    f32x4 acc[4][2] = {};
    const int rbase = t >> 4;
    const int scol = (t & 15) * 4;
    const float* __restrict__ xg = x + (size_t)(bm * BM) * KDIM + scol;
    const float* __restrict__ wg = W1 + (size_t)(bn * BN) * KDIM + scol;
    for (int k0 = 0; k0 < KDIM; k0 += BK) {
#pragma unroll
        for (int rr = 0; rr < 8; ++rr) {
            int row = rr * 16 + rbase;
            float4 v = *reinterpret_cast<const float4*>(xg + (size_t)row * KDIM + k0);
            bf16x4 h = { (__bf16)v.x, (__bf16)v.y, (__bf16)v.z, (__bf16)v.w };
            *reinterpret_cast<bf16x4*>(&As[row * LDK + scol]) = h;
        }
#pragma unroll
        for (int rr = 0; rr < 4; ++rr) {
            int row = rr * 16 + rbase;
            float4 v = *reinterpret_cast<const float4*>(wg + (size_t)row * KDIM + k0);
            bf16x4 h = { (__bf16)v.x, (__bf16)v.y, (__bf16)v.z, (__bf16)v.w };
            *reinterpret_cast<bf16x4*>(&Bs[row * LDK + scol]) = h;
        }
        __syncthreads();
#pragma unroll
        for (int kk = 0; kk < BK; kk += 32) {
            bf16x8 af[4];
            bf16x8 bfr[2];
#pragma unroll
            for (int mi = 0; mi < 4; ++mi)
                af[mi] = *reinterpret_cast<const bf16x8*>(
                    &As[(wm + mi * 16 + lrow) * LDK + kk + quad * 8]);
#pragma unroll
            for (int ni = 0; ni < 2; ++ni)
                bfr[ni] = *reinterpret_cast<const bf16x8*>(
                    &Bs[(wn + ni * 16 + lrow) * LDK + kk + quad * 8]);
#pragma unroll
            for (int mi = 0; mi < 4; ++mi)
#pragma unroll
                for (int ni = 0; ni < 2; ++ni)
                    acc[mi][ni] = __builtin_amdgcn_mfma_f32_16x16x32_bf16(
                        af[mi], bfr[ni], acc[mi][ni], 0, 0, 0);
        }
        __syncthreads();
    }
    const int gmb = bm * BM + wm;
    const int gnb = bn * BN + wn;
#pragma unroll
    for (int ni = 0; ni < 2; ++ni) {
        const int gn = gnb + ni * 16 + lrow;
        const float bias = b1[gn];
#pragma unroll
        for (int mi = 0; mi < 4; ++mi) {
            const int gm0 = gmb + mi * 16 + quad * 4;
#pragma unroll
            for (int r = 0; r < 4; ++r) {
                const int gm = gm0 + r;
                float z = acc[mi][ni][r] + bias;
                y[(size_t)gm * NDIM + gn] =
                    x[(size_t)gm * NDIM + gn] * softplus_f(z) * s[gm];
            }
        }
    }
}

extern "C" void kernel_launch(void* const* d_in, const int* in_sizes, int n_in,
                              void* d_out, int out_size, void* d_ws, size_t ws_size,
                              hipStream_t stream) {
    const float* x  = (const float*)d_in[0];
    const float* W1 = (const float*)d_in[1];
    const float* b1 = (const float*)d_in[2];
    const float* W2 = (const float*)d_in[3];
    const float* b2 = (const float*)d_in[4];
    const float* W3 = (const float*)d_in[5];
    const float* b3 = (const float*)d_in[6];
    // d_in[7] = A : unused

    float* y = (float*)d_out;

    const size_t XB_BYTES = (size_t)MDIM * KDIM * 2;   // 8 MB
    const size_t WB_BYTES = (size_t)NDIM * KDIM * 2;   // 2 MB
    const size_t S_BYTES  = (size_t)MDIM * 4;          // 16 KB

    if (ws_size >= XB_BYTES + WB_BYTES + S_BYTES) {
        __bf16* xb  = (__bf16*)d_ws;
        __bf16* w1b = (__bf16*)((char*)d_ws + XB_BYTES);
        float*  s   = (float*)((char*)d_ws + XB_BYTES + WB_BYTES);
        prep2<<<dim3(MDIM / 16), dim3(256), 0, stream>>>(
            x, W1, W2, b2, W3, b3, xb, w1b, s);
        gemm_bf<<<dim3(NDIM / GBN, MDIM / GBM), dim3(256), 0, stream>>>(
            xb, w1b, x, b1, s, y);
    } else {
        float* s = (float*)d_ws;
        s_kernel_fb<<<dim3(MDIM), dim3(256), 0, stream>>>(x, W2, b2, W3, b3, s);
        gemm_fused_fb<<<dim3(NDIM / BN, MDIM / BM), dim3(256), 0, stream>>>(x, W1, b1, s, y);
    }
}